// Round 2
// baseline (110.601 us; speedup 1.0000x reference)
//
#include <hip/hip_runtime.h>

// ConsolidateBits: pack every 32 consecutive (x > 0.5) predicates into one
// uint32 (bit i -> position i). Pure HBM stream: 512 MiB read + 16 MiB write.
//
// R1 strategy: make lane order == element order so __ballot IS the answer.
//   - wave handles 512 consecutive elements per iteration
//   - lane loads x[base + seg*64 + lane] for seg = 0..7 (8 independent
//     coalesced dword loads, 2 KiB in flight per wave)
//   - b_seg = __ballot(v > 0.5f): bit i == element base+seg*64+i
//     == output words {base/32 + 2*seg, +1} directly (no shuffles, no LDS)
//   - lanes 0..7 store the 8 ballots as 64-bit words (64 B coalesced store)

__global__ __launch_bounds__(256) void ConsolidateBits_35888746725585_kernel(
    const float* __restrict__ x,
    unsigned long long* __restrict__ out64,
    long long n) {
    const int lane = threadIdx.x & 63;
    const long long wave   = ((long long)blockIdx.x * blockDim.x + threadIdx.x) >> 6;
    const long long nwaves = ((long long)gridDim.x * blockDim.x) >> 6;

    const long long STEP = 512;                 // elements per wave-iteration
    const long long nfull = n & ~(STEP - 1);

    for (long long base = wave * STEP; base < nfull; base += nwaves * STEP) {
        const float* p = x + base + lane;
        // 8 independent coalesced loads (offsets fold to immediates).
        float v0 = p[0];
        float v1 = p[64];
        float v2 = p[128];
        float v3 = p[192];
        float v4 = p[256];
        float v5 = p[320];
        float v6 = p[384];
        float v7 = p[448];
        unsigned long long b0 = __ballot(v0 > 0.5f);
        unsigned long long b1 = __ballot(v1 > 0.5f);
        unsigned long long b2 = __ballot(v2 > 0.5f);
        unsigned long long b3 = __ballot(v3 > 0.5f);
        unsigned long long b4 = __ballot(v4 > 0.5f);
        unsigned long long b5 = __ballot(v5 > 0.5f);
        unsigned long long b6 = __ballot(v6 > 0.5f);
        unsigned long long b7 = __ballot(v7 > 0.5f);
        if (lane < 8) {
            // Ballots are wave-uniform (SGPR pairs); pick by lane, store 64B.
            unsigned long long b =
                lane == 0 ? b0 : lane == 1 ? b1 : lane == 2 ? b2 :
                lane == 3 ? b3 : lane == 4 ? b4 : lane == 5 ? b5 :
                lane == 6 ? b6 : b7;
            out64[(base >> 6) + lane] = b;
        }
    }

    // Tail for n not a multiple of 512 (not hit for 2^27, kept for safety).
    if (wave == 0) {
        unsigned int* out32 = (unsigned int*)out64;
        for (long long base = nfull; base < n; base += 64) {
            long long e = base + lane;
            bool pred = (e < n) && (x[e] > 0.5f);
            unsigned long long b = __ballot(pred);
            if (lane == 0) {
                out32[base >> 5] = (unsigned int)b;
                if (base + 32 < n) out32[(base >> 5) + 1] = (unsigned int)(b >> 32);
            }
        }
    }
}

extern "C" void kernel_launch(void* const* d_in, const int* in_sizes, int n_in,
                              void* d_out, int out_size, void* d_ws, size_t ws_size,
                              hipStream_t stream) {
    const float* x = (const float*)d_in[0];
    unsigned long long* out64 = (unsigned long long*)d_out;
    const long long n = (long long)in_sizes[0];  // 4096*32768 = 134217728

    const int threads = 256;
    // 2048 blocks = 8 blocks/CU on 256 CUs = 32 waves/CU (full occupancy);
    // grid-stride covers the rest.
    const int blocks = 2048;
    hipLaunchKernelGGL(ConsolidateBits_35888746725585_kernel,
                       dim3(blocks), dim3(threads), 0, stream,
                       x, out64, n);
}

// Round 3
// 94.094 us; speedup vs baseline: 1.1754x; 1.1754x over previous
//
#include <hip/hip_runtime.h>

// ConsolidateBits: pack every 32 consecutive (x > 0.5) predicates into one
// uint32 (bit i -> position i). Pure HBM stream: 512 MiB read + 16 MiB write.
//
// R2 strategy (keep 16B/lane loads, kill the LDS pipe + partial-line writes):
//   - one-shot grid: wave owns 512 consecutive elements (2 KiB)
//   - 8-lane group k owns 64 consecutive elems: lane j loads float4 at
//     +64k+4j and +64k+32+4j (two coalesced dwordx4 insts, 2 in flight)
//   - nibble<<4j, OR-reduce across the 8-lane group with DPP (VALU-only:
//     quad_perm[1,0,3,2], quad_perm[2,3,0,1], row_half_mirror) — no
//     ds_swizzle, no lgkmcnt waits, SQ_LDS_BANK_CONFLICT must be 0
//   - group's two words are ADJACENT -> lane j==0 stores one u64;
//     8 lanes x 8 B = one full aligned 64-B line per wave (dwordx2)

typedef unsigned int u32;
typedef unsigned long long u64;

__device__ __forceinline__ u32 group8_or(u32 v) {
    u32 t;
    t = __builtin_amdgcn_mov_dpp(v, 0xB1, 0xF, 0xF, 1);  v |= t;  // xor 1 (quad_perm [1,0,3,2])
    t = __builtin_amdgcn_mov_dpp(v, 0x4E, 0xF, 0xF, 1);  v |= t;  // xor 2 (quad_perm [2,3,0,1])
    t = __builtin_amdgcn_mov_dpp(v, 0x141, 0xF, 0xF, 1); v |= t;  // row_half_mirror: quad<->quad within 8
    return v;
}

__device__ __forceinline__ u32 pack4(float4 v) {
    return (u32)(v.x > 0.5f)        |
           ((u32)(v.y > 0.5f) << 1) |
           ((u32)(v.z > 0.5f) << 2) |
           ((u32)(v.w > 0.5f) << 3);
}

__global__ __launch_bounds__(256) void ConsolidateBits_35888746725585_kernel(
    const float* __restrict__ x,
    u64* __restrict__ out64,
    long long n) {
    const int lane = threadIdx.x & 63;
    const int k = lane >> 3;          // 8-lane group id within wave
    const int j = lane & 7;           // lane within group
    const long long wave = ((long long)blockIdx.x * blockDim.x + threadIdx.x) >> 6;
    const long long base = wave << 9; // 512 elements per wave

    if (base + 512 <= n) {
        const long long e0 = base + 64 * k + 4 * j;
        const float4 a = *reinterpret_cast<const float4*>(x + e0);        // elems [64k, 64k+32) of chunk
        const float4 b = *reinterpret_cast<const float4*>(x + e0 + 32);   // elems [64k+32, 64k+64)
        u32 wa = pack4(a) << (4 * j);
        u32 wb = pack4(b) << (4 * j);
        wa = group8_or(wa);
        wb = group8_or(wb);
        if (j == 0) {
            // group k's 64 elems == u64 word (base>>6)+k; low u32 = first 32 elems
            out64[(base >> 6) + k] = (u64)wa | ((u64)wb << 32);
        }
    } else if (base < n) {
        // Masked tail (not hit for n = 2^27; safety for arbitrary n%512)
        u32* out32 = (u32*)out64;
        for (long long s = base; s < n && s < base + 512; s += 64) {
            long long e = s + lane;
            bool p = (e < n) && (x[e] > 0.5f);
            u64 bb = __ballot(p);
            if (lane == 0) {
                out32[s >> 5] = (u32)bb;
                if (s + 32 < n) out32[(s >> 5) + 1] = (u32)(bb >> 32);
            }
        }
    }
}

extern "C" void kernel_launch(void* const* d_in, const int* in_sizes, int n_in,
                              void* d_out, int out_size, void* d_ws, size_t ws_size,
                              hipStream_t stream) {
    const float* x = (const float*)d_in[0];
    u64* out64 = (u64*)d_out;
    const long long n = (long long)in_sizes[0];  // 4096*32768 = 134217728

    const int threads = 256;
    const long long nwaves = (n + 511) >> 9;          // one wave per 512 elems
    const long long blocks = (nwaves + 3) >> 2;       // 4 waves per block
    hipLaunchKernelGGL(ConsolidateBits_35888746725585_kernel,
                       dim3((unsigned)blocks), dim3(threads), 0, stream,
                       x, out64, n);
}

// Round 5
// 86.275 us; speedup vs baseline: 1.2820x; 1.0906x over previous
//
#include <hip/hip_runtime.h>

// ConsolidateBits: pack every 32 consecutive (x > 0.5) predicates into one
// uint32 (bit i -> position i). Pure HBM stream: 512 MiB read + 16 MiB write.
//
// R4 = R3 with native clang vector types for the nontemporal builtins
// (HIP_vector_type structs are rejected; ext_vector_type(4) lowers to the
// same dwordx4 with the nt cache bit).
//   - wave owns 1024 consecutive elements (4 KiB); one-shot grid
//   - 8-lane group k owns 128 consecutive elems: lane j issues FOUR
//     nontemporal dwordx4 loads (e0, +32, +64, +96) -> 4 loads in flight
//   - pack4 + shift + DPP OR-reduce (VALU-only, no LDS pipe)
//   - group leader stores 4 words (dwordx4, nontemporal):
//     8 groups x 16 B = 128 B contiguous per wave

typedef unsigned int u32;
typedef unsigned long long u64;
typedef float f32x4 __attribute__((ext_vector_type(4)));
typedef u32 u32x4 __attribute__((ext_vector_type(4)));

__device__ __forceinline__ u32 group8_or(u32 v) {
    u32 t;
    t = __builtin_amdgcn_mov_dpp(v, 0xB1, 0xF, 0xF, 1);  v |= t;  // quad_perm xor1
    t = __builtin_amdgcn_mov_dpp(v, 0x4E, 0xF, 0xF, 1);  v |= t;  // quad_perm xor2
    t = __builtin_amdgcn_mov_dpp(v, 0x141, 0xF, 0xF, 1); v |= t;  // row_half_mirror (xor4 within 8)
    return v;
}

__device__ __forceinline__ u32 pack4(f32x4 v) {
    return (u32)(v.x > 0.5f)        |
           ((u32)(v.y > 0.5f) << 1) |
           ((u32)(v.z > 0.5f) << 2) |
           ((u32)(v.w > 0.5f) << 3);
}

__global__ __launch_bounds__(256) void ConsolidateBits_35888746725585_kernel(
    const float* __restrict__ x,
    u32* __restrict__ out32,
    long long n) {
    const int lane = threadIdx.x & 63;
    const int k = lane >> 3;           // 8-lane group id
    const int j = lane & 7;            // lane within group
    const long long wave = ((long long)blockIdx.x * blockDim.x + threadIdx.x) >> 6;
    const long long base = wave << 10; // 1024 elements per wave

    if (base + 1024 <= n) {
        const f32x4* p4 = reinterpret_cast<const f32x4*>(x + base + 128 * k + 4 * j);
        // 4 independent nontemporal dwordx4 loads (offsets fold to immediates).
        f32x4 a0 = __builtin_nontemporal_load(p4);       // group elems [  0, 32)
        f32x4 a1 = __builtin_nontemporal_load(p4 + 8);   //             [ 32, 64)
        f32x4 a2 = __builtin_nontemporal_load(p4 + 16);  //             [ 64, 96)
        f32x4 a3 = __builtin_nontemporal_load(p4 + 24);  //             [ 96,128)
        const int sh = 4 * j;
        u32 w0 = group8_or(pack4(a0) << sh);
        u32 w1 = group8_or(pack4(a1) << sh);
        u32 w2 = group8_or(pack4(a2) << sh);
        u32 w3 = group8_or(pack4(a3) << sh);
        if (j == 0) {
            u32x4 w = {w0, w1, w2, w3};
            u32x4* dst = reinterpret_cast<u32x4*>(out32 + (base >> 5) + 4 * k);
            __builtin_nontemporal_store(w, dst);
        }
    } else if (base < n) {
        // Masked tail (not hit for n = 2^27; safety for arbitrary n%1024)
        for (long long s = base; s < n && s < base + 1024; s += 64) {
            long long e = s + lane;
            bool pred = (e < n) && (x[e] > 0.5f);
            u64 bb = __ballot(pred);
            if (lane == 0) {
                out32[s >> 5] = (u32)bb;
                if (s + 32 < n) out32[(s >> 5) + 1] = (u32)(bb >> 32);
            }
        }
    }
}

extern "C" void kernel_launch(void* const* d_in, const int* in_sizes, int n_in,
                              void* d_out, int out_size, void* d_ws, size_t ws_size,
                              hipStream_t stream) {
    const float* x = (const float*)d_in[0];
    u32* out32 = (u32*)d_out;
    const long long n = (long long)in_sizes[0];  // 4096*32768 = 134217728

    const int threads = 256;
    const long long nwaves = (n + 1023) >> 10;   // one wave per 1024 elems
    const long long blocks = (nwaves + 3) >> 2;  // 4 waves per block
    hipLaunchKernelGGL(ConsolidateBits_35888746725585_kernel,
                       dim3((unsigned)blocks), dim3(threads), 0, stream,
                       x, out32, n);
}